// Round 1
// baseline (1104.789 us; speedup 1.0000x reference)
//
#include <hip/hip_runtime.h>
#include <cstdint>

#define RASTN 256
#define TILE 16
#define FARV 10.0f

__device__ __forceinline__ float gval(int i) {
    // g = 2*(i+0.5)/256 - 1  -- exact in f32 (multiples of 1/256)
    return (2.0f * ((float)i + 0.5f)) / 256.0f - 1.0f;
}

// -------- Kernel 1: project vertices -> uvz (replicates _project bit-exactly) -----
__global__ __launch_bounds__(256) void proj_kernel(
    const float* __restrict__ verts, const float* __restrict__ Km,
    const float* __restrict__ Rm, const float* __restrict__ tm,
    const float* __restrict__ dm, float* __restrict__ uvz,
    int total, int V)
{
#pragma clang fp contract(off)
    int idx = blockIdx.x * blockDim.x + threadIdx.x;
    if (idx >= total) return;
    int b = idx / V;
    const float* R = Rm + b * 9;
    const float* K = Km + b * 9;
    const float* t = tm + b * 3;
    const float* d = dm + b * 5;
    float vx = verts[(size_t)idx*3+0], vy = verts[(size_t)idx*3+1], vz = verts[(size_t)idx*3+2];
    // einsum('bvj,bij->bvi') + t : row-dot; R==I,t==0 in data so any order is exact,
    // but keep the canonical order anyway.
    float cxm = ((vx*R[0] + vy*R[1]) + vz*R[2]) + t[0];
    float cym = ((vx*R[3] + vy*R[4]) + vz*R[5]) + t[1];
    float czm = ((vx*R[6] + vy*R[7]) + vz*R[8]) + t[2];
    float zd = czm + 1e-9f;
    float x_ = cxm / zd;
    float y_ = cym / zd;
    float k1 = d[0], k2 = d[1], p1 = d[2], p2 = d[3], k3 = d[4];
    float r2   = (x_*x_) + (y_*y_);
    float r2_2 = r2 * r2;        // integer_pow(r2,2)
    float r2_3 = r2 * r2_2;      // integer_pow(r2,3) = x * (x*x)
    float radial = ((1.0f + k1*r2) + k2*r2_2) + k3*r2_3;
    float x__ = ((x_*radial) + (((2.0f*p1)*x_)*y_)) + (p2*(r2 + 2.0f*(x_*x_)));
    float y__ = ((y_*radial) + (p1*(r2 + 2.0f*(y_*y_)))) + (((2.0f*p2)*x_)*y_);
    // pts . K rows (third row unused downstream)
    float up = ((x__*K[0]) + (y__*K[1])) + (1.0f*K[2]);
    float vp = ((x__*K[3]) + (y__*K[4])) + (1.0f*K[5]);
    vp = 256.0f - vp;                           // ORIG_H - vv
    float un = (2.0f*(up - 128.0f)) / 256.0f;
    float vn = (2.0f*(vp - 128.0f)) / 256.0f;
    uvz[(size_t)idx*3+0] = un;
    uvz[(size_t)idx*3+1] = vn;
    uvz[(size_t)idx*3+2] = czm;
}

// -------- Kernel 2: per-triangle setup records (16 floats each) -------------------
// r0 = (minx, maxx, miny, maxy)   margined bbox; dead -> inverted bbox
// r1 = (cx, cy, by-cy, cx-bx)
// r2 = (cy-ay, ax-cx, den_s, sign(den_s))
// r3 = (zs(az), zs(bz), zs(cz), 0)
__global__ __launch_bounds__(256) void prep_kernel(
    const float* __restrict__ uvz, const int* __restrict__ faces,
    float4* __restrict__ rec, int total, int F2, int F, int V)
{
#pragma clang fp contract(off)
    int idx = blockIdx.x * blockDim.x + threadIdx.x;
    if (idx >= total) return;
    int b = idx / F2;
    int j = idx - b * F2;
    const int* fb = faces + (size_t)b * F * 3;
    int i0, i1, i2;
    if (j < F) { i0 = fb[j*3+0]; i1 = fb[j*3+1]; i2 = fb[j*3+2]; }
    else { int jj = j - F; i0 = fb[jj*3+2]; i1 = fb[jj*3+1]; i2 = fb[jj*3+0]; }
    const float* ub = uvz + (size_t)b * V * 3;
    float ax = ub[i0*3+0], ay = ub[i0*3+1], az = ub[i0*3+2];
    float bx = ub[i1*3+0], by = ub[i1*3+1], bz = ub[i1*3+2];
    float cx = ub[i2*3+0], cy = ub[i2*3+1], cz = ub[i2*3+2];
    float den = (bx-ax)*(cy-ay) - (by-ay)*(cx-ax);
    bool ok = fabsf(den) > 1e-8f;
    float dens = ok ? den : 1.0f;
    bool alive = ok && (az > 1e-8f) && (bz > 1e-8f) && (cz > 1e-8f);
    float za = (az > 1e-8f) ? az : 1.0f;
    float zb = (bz > 1e-8f) ? bz : 1.0f;
    float zc = (cz > 1e-8f) ? cz : 1.0f;
    float mnx = fminf(ax, fminf(bx, cx));
    float mxx = fmaxf(ax, fmaxf(bx, cx));
    float mny = fminf(ay, fminf(by, cy));
    float mxy = fmaxf(ay, fmaxf(by, cy));
    // conservative margin: absolute + relative to coordinate magnitude
    float m = 1e-3f + 1e-6f*((fabsf(mnx)+fabsf(mxx))+(fabsf(mny)+fabsf(mxy)));
    mnx -= m; mxx += m; mny -= m; mxy += m;
    // cull fully off-screen (pixel centers lie inside [-1,1])
    if (!(mxx >= -1.0f) || !(mnx <= 1.0f) || !(mxy >= -1.0f) || !(mny <= 1.0f)) alive = false;
    if (!alive) { mnx = 3e38f; mxx = -3e38f; mny = 3e38f; mxy = -3e38f; }
    size_t base = (size_t)idx * 4;
    rec[base+0] = make_float4(mnx, mxx, mny, mxy);
    rec[base+1] = make_float4(cx, cy, by - cy, cx - bx);
    rec[base+2] = make_float4(cy - ay, ax - cx, dens, dens > 0.0f ? 1.0f : -1.0f);
    rec[base+3] = make_float4(za, zb, zc, 0.0f);
}

// -------- Kernel 3: tiled rasterizer --------------------------------------------
__global__ __launch_bounds__(256) void raster_kernel(
    const float4* __restrict__ rec, float* __restrict__ zout,
    float* __restrict__ mout, int F2)
{
#pragma clang fp contract(off)
    __shared__ float4 sh[256*4];           // 16 KiB staged compacted records
    __shared__ int s_wcnt[4], s_woff[4], s_tot;
    int tx = threadIdx.x, ty = threadIdx.y;
    int tid = ty*TILE + tx;
    int lane = tid & 63, wv = tid >> 6;
    int b = blockIdx.z;
    int col = blockIdx.x*TILE + tx;
    int row = blockIdx.y*TILE + ty;
    float X = gval(col), Y = gval(row);
    float txmin = gval(blockIdx.x*TILE), txmax = gval(blockIdx.x*TILE + TILE-1);
    float tymin = gval(blockIdx.y*TILE), tymax = gval(blockIdx.y*TILE + TILE-1);
    float maxinv = 0.0f;
    bool cov = false;
    int nchunks = (F2 + 255) / 256;
    const float4* rb = rec + (size_t)b * F2 * 4;
    for (int c = 0; c < nchunks; ++c) {
        int t = c*256 + tid;
        float4 r0 = make_float4(0,0,0,0), r1 = r0, r2 = r0, r3 = r0;
        bool keep = false;
        if (t < F2) {
            r0 = rb[(size_t)t*4+0];
            keep = !(r0.y < txmin || r0.x > txmax || r0.w < tymin || r0.z > tymax);
            if (keep) { r1 = rb[(size_t)t*4+1]; r2 = rb[(size_t)t*4+2]; r3 = rb[(size_t)t*4+3]; }
        }
        unsigned long long bm = __ballot(keep ? 1 : 0);
        int wcnt = __popcll(bm);
        int pfx = __popcll(bm & ((1ull << lane) - 1ull));
        if (lane == 0) s_wcnt[wv] = wcnt;
        __syncthreads();
        if (tid == 0) {
            int acc = 0;
            for (int k = 0; k < 4; ++k) { s_woff[k] = acc; acc += s_wcnt[k]; }
            s_tot = acc;
        }
        __syncthreads();
        if (keep) {
            int p = s_woff[wv] + pfx;
            sh[p*4+0] = r0; sh[p*4+1] = r1; sh[p*4+2] = r2; sh[p*4+3] = r3;
        }
        __syncthreads();
        int nk = s_tot;
        for (int i = 0; i < nk; ++i) {
            float4 q0 = sh[i*4+0];                 // wave-uniform address: LDS broadcast
            if (X < q0.x || X > q0.y || Y < q0.z || Y > q0.w) continue;
            float4 q1 = sh[i*4+1];
            float4 q2 = sh[i*4+2];
            float xc = X - q1.x;
            float yc = Y - q1.y;
            float e0 = (q1.z*xc) + (q1.w*yc);      // == w0 numerator, bit-exact vs ref
            float e1 = (q2.x*xc) + (q2.y*yc);      // == w1 numerator
            float dens = q2.z, sgn = q2.w;
            // conservative sign prefilters (slack covers -0/underflow edge cases);
            // the exact tests inside decide.
            float s0 = e0*sgn, s1 = e1*sgn;
            float s2 = ((dens - e0) - e1)*sgn;
            float eps2 = 1e-5f*((fabsf(dens)+fabsf(e0))+fabsf(e1));
            if (s0 > -1e-30f && s1 > -1e-30f && s2 > -eps2) {
                float4 q3 = sh[i*4+3];
                float w0 = e0 / dens;              // IEEE div == ref
                float w1 = e1 / dens;
                float w2 = (1.0f - w0) - w1;
                float inv = ((w0/q3.x) + (w1/q3.y)) + (w2/q3.z);
                if ((w0 >= 0.0f) && (w1 >= 0.0f) && (w2 >= 0.0f) && (inv > 1e-8f)) {
                    maxinv = fmaxf(maxinv, inv);
                    cov = true;
                }
            }
        }
        __syncthreads();
    }
    // min over valid of fl(1/inv) == fl(1/max inv)  (monotone correctly-rounded div)
    float zb = cov ? fminf(FARV, 1.0f / maxinv) : FARV;
    size_t pix = ((size_t)b*RASTN + row)*RASTN + col;
    zout[pix] = zb;
    mout[pix] = cov ? 1.0f : 0.0f;
}

// -------- Kernel 4: per-batch max(no_back)/min reduction -------------------------
__global__ __launch_bounds__(256) void minmax_kernel(
    const float* __restrict__ zb, float* __restrict__ mm, int npix)
{
    __shared__ float smx[256], smn[256];
    int b = blockIdx.x;
    const float* p = zb + (size_t)b * npix;
    float vmx = -3e38f, vmn = 3e38f;
    for (int i = threadIdx.x; i < npix; i += 256) {
        float z = p[i];
        float nb = (z == FARV) ? 0.0f : z;   // (1-img_inf)*img
        vmx = fmaxf(vmx, nb);
        vmn = fminf(vmn, z);
    }
    smx[threadIdx.x] = vmx; smn[threadIdx.x] = vmn;
    __syncthreads();
    for (int s = 128; s > 0; s >>= 1) {
        if (threadIdx.x < s) {
            smx[threadIdx.x] = fmaxf(smx[threadIdx.x], smx[threadIdx.x+s]);
            smn[threadIdx.x] = fminf(smn[threadIdx.x], smn[threadIdx.x+s]);
        }
        __syncthreads();
    }
    if (threadIdx.x == 0) { mm[b*2] = smx[0]; mm[b*2+1] = smn[0]; }
}

// -------- Kernel 5: normalize depth in place -------------------------------------
__global__ __launch_bounds__(256) void final_kernel(
    float* __restrict__ zdep, const float* __restrict__ mm, int npix, int total)
{
#pragma clang fp contract(off)
    int idx = blockIdx.x*256 + threadIdx.x;
    if (idx >= total) return;
    int b = idx / npix;
    float mx = mm[b*2], mn = mm[b*2+1];
    float z = zdep[idx];
    float nd = (mx - z) / ((mx - mn) + 1e-4f);
    // jnp.clip semantics: NaN propagates
    float cv = nd;
    cv = (cv < 0.0f) ? 0.0f : cv;
    cv = (cv > 1.0f) ? 1.0f : cv;
    zdep[idx] = cv;
}

extern "C" void kernel_launch(void* const* d_in, const int* in_sizes, int n_in,
                              void* d_out, int out_size, void* d_ws, size_t ws_size,
                              hipStream_t stream)
{
    const float* verts = (const float*)d_in[0];
    const int*   faces = (const int*)d_in[1];
    const float* Km    = (const float*)d_in[2];
    const float* Rm    = (const float*)d_in[3];
    const float* tm    = (const float*)d_in[4];
    const float* dm    = (const float*)d_in[5];
    float* out = (float*)d_out;

    int B  = in_sizes[2] / 9;          // intr is B*3*3
    int V  = in_sizes[0] / (3 * B);
    int F  = in_sizes[1] / (3 * B);
    int F2 = 2 * F;
    int npix = RASTN * RASTN;

    char* ws = (char*)d_ws;
    float* uvz = (float*)ws;
    size_t o_rec = (((size_t)B * V * 3 * sizeof(float)) + 255) & ~(size_t)255;
    float4* rec = (float4*)(ws + o_rec);
    size_t o_mm = ((o_rec + (size_t)B * F2 * 4 * sizeof(float4)) + 255) & ~(size_t)255;
    float* mm = (float*)(ws + o_mm);

    float* zdep = out;                       // depth region doubles as zbuf
    float* mask = out + (size_t)B * npix;

    int totV = B * V;
    proj_kernel<<<(totV + 255) / 256, 256, 0, stream>>>(verts, Km, Rm, tm, dm, uvz, totV, V);
    int totT = B * F2;
    prep_kernel<<<(totT + 255) / 256, 256, 0, stream>>>(uvz, faces, rec, totT, F2, F, V);
    dim3 grid(RASTN / TILE, RASTN / TILE, B), blk(TILE, TILE);
    raster_kernel<<<grid, blk, 0, stream>>>(rec, zdep, mask, F2);
    minmax_kernel<<<B, 256, 0, stream>>>(zdep, mm, npix);
    final_kernel<<<(B * npix + 255) / 256, 256, 0, stream>>>(zdep, mm, npix, B * npix);
}

// Round 2
// 693.368 us; speedup vs baseline: 1.5934x; 1.5934x over previous
//
#include <hip/hip_runtime.h>
#include <cstdint>

#define RASTN 256
#define FARV 10.0f
#define FARBITS 0x41200000u   // bits of 10.0f

__device__ __forceinline__ float gval(int i) {
    // g = 2*(i+0.5)/256 - 1  -- exact in f32 (multiples of 1/256)
    return (2.0f * ((float)i + 0.5f)) / 256.0f - 1.0f;
}

// -------- Kernel 1: project vertices -> uvz (replicates _project bit-exactly) -----
__global__ __launch_bounds__(256) void proj_kernel(
    const float* __restrict__ verts, const float* __restrict__ Km,
    const float* __restrict__ Rm, const float* __restrict__ tm,
    const float* __restrict__ dm, float* __restrict__ uvz,
    int total, int V)
{
#pragma clang fp contract(off)
    int idx = blockIdx.x * blockDim.x + threadIdx.x;
    if (idx >= total) return;
    int b = idx / V;
    const float* R = Rm + b * 9;
    const float* K = Km + b * 9;
    const float* t = tm + b * 3;
    const float* d = dm + b * 5;
    float vx = verts[(size_t)idx*3+0], vy = verts[(size_t)idx*3+1], vz = verts[(size_t)idx*3+2];
    float cxm = ((vx*R[0] + vy*R[1]) + vz*R[2]) + t[0];
    float cym = ((vx*R[3] + vy*R[4]) + vz*R[5]) + t[1];
    float czm = ((vx*R[6] + vy*R[7]) + vz*R[8]) + t[2];
    float zd = czm + 1e-9f;
    float x_ = cxm / zd;
    float y_ = cym / zd;
    float k1 = d[0], k2 = d[1], p1 = d[2], p2 = d[3], k3 = d[4];
    float r2   = (x_*x_) + (y_*y_);
    float r2_2 = r2 * r2;
    float r2_3 = r2 * r2_2;
    float radial = ((1.0f + k1*r2) + k2*r2_2) + k3*r2_3;
    float x__ = ((x_*radial) + (((2.0f*p1)*x_)*y_)) + (p2*(r2 + 2.0f*(x_*x_)));
    float y__ = ((y_*radial) + (p1*(r2 + 2.0f*(y_*y_)))) + (((2.0f*p2)*x_)*y_);
    float up = ((x__*K[0]) + (y__*K[1])) + (1.0f*K[2]);
    float vp = ((x__*K[3]) + (y__*K[4])) + (1.0f*K[5]);
    vp = 256.0f - vp;
    float un = (2.0f*(up - 128.0f)) / 256.0f;
    float vn = (2.0f*(vp - 128.0f)) / 256.0f;
    uvz[(size_t)idx*3+0] = un;
    uvz[(size_t)idx*3+1] = vn;
    uvz[(size_t)idx*3+2] = czm;
}

// -------- Kernel 2: per-triangle setup records (4x float4 each) -------------------
// r0 = (cx, cy, by-cy, cx-bx)
// r1 = (cy-ay, ax-cx, den_s, sign(den_s))
// r2 = (zs(az), zs(bz), zs(cz), 0)
// r3 = int bits: (c0, c1, r0, r1) conservative pixel bbox; dead -> c1<c0
__global__ __launch_bounds__(256) void prep_kernel(
    const float* __restrict__ uvz, const int* __restrict__ faces,
    float4* __restrict__ rec, int total, int F2, int F, int V)
{
#pragma clang fp contract(off)
    int idx = blockIdx.x * blockDim.x + threadIdx.x;
    if (idx >= total) return;
    int b = idx / F2;
    int j = idx - b * F2;
    const int* fb = faces + (size_t)b * F * 3;
    int i0, i1, i2;
    if (j < F) { i0 = fb[j*3+0]; i1 = fb[j*3+1]; i2 = fb[j*3+2]; }
    else { int jj = j - F; i0 = fb[jj*3+2]; i1 = fb[jj*3+1]; i2 = fb[jj*3+0]; }
    const float* ub = uvz + (size_t)b * V * 3;
    float ax = ub[i0*3+0], ay = ub[i0*3+1], az = ub[i0*3+2];
    float bx = ub[i1*3+0], by = ub[i1*3+1], bz = ub[i1*3+2];
    float cx = ub[i2*3+0], cy = ub[i2*3+1], cz = ub[i2*3+2];
    float den = (bx-ax)*(cy-ay) - (by-ay)*(cx-ax);
    bool ok = fabsf(den) > 1e-8f;
    float dens = ok ? den : 1.0f;
    bool alive = ok && (az > 1e-8f) && (bz > 1e-8f) && (cz > 1e-8f);
    float za = (az > 1e-8f) ? az : 1.0f;
    float zb = (bz > 1e-8f) ? bz : 1.0f;
    float zc = (cz > 1e-8f) ? cz : 1.0f;
    float mnx = fminf(ax, fminf(bx, cx));
    float mxx = fmaxf(ax, fmaxf(bx, cx));
    float mny = fminf(ay, fminf(by, cy));
    float mxy = fmaxf(ay, fmaxf(by, cy));
    // conservative margin: absolute + relative (same logic that passed in R0)
    float m = 1e-3f + 1e-6f*((fabsf(mnx)+fabsf(mxx))+(fabsf(mny)+fabsf(mxy)));
    mnx -= m; mxx += m; mny -= m; mxy += m;
    // cull fully off-screen (pixel centers lie inside [-1,1])
    if (!(mxx >= -1.0f) || !(mnx <= 1.0f) || !(mxy >= -1.0f) || !(mny <= 1.0f)) alive = false;
    int ic0 = 1, ic1 = 0, ir0 = 1, ir1 = 0;   // empty
    if (alive) {
        // clamp to a safe float range before int conversion (avoids overflow UB)
        float lx = fmaxf(mnx, -1.5f), hx = fminf(mxx, 1.5f);
        float ly = fmaxf(mny, -1.5f), hy = fminf(mxy, 1.5f);
        // pixel c has X=(c+0.5)/128-1; conservative floor/ceil both directions
        ic0 = (int)floorf((lx + 1.0f) * 128.0f - 0.5f);
        ic1 = (int)ceilf ((hx + 1.0f) * 128.0f - 0.5f);
        ir0 = (int)floorf((ly + 1.0f) * 128.0f - 0.5f);
        ir1 = (int)ceilf ((hy + 1.0f) * 128.0f - 0.5f);
        ic0 = ic0 < 0 ? 0 : ic0;  ir0 = ir0 < 0 ? 0 : ir0;
        ic1 = ic1 > 255 ? 255 : ic1;  ir1 = ir1 > 255 ? 255 : ir1;
        if (ic0 > ic1 || ir0 > ir1) { ic0 = 1; ic1 = 0; ir0 = 1; ir1 = 0; }
    }
    size_t base = (size_t)idx * 4;
    rec[base+0] = make_float4(cx, cy, by - cy, cx - bx);
    rec[base+1] = make_float4(cy - ay, ax - cx, dens, dens > 0.0f ? 1.0f : -1.0f);
    rec[base+2] = make_float4(za, zb, zc, 0.0f);
    rec[base+3] = make_float4(__int_as_float(ic0), __int_as_float(ic1),
                              __int_as_float(ir0), __int_as_float(ir1));
}

// -------- Kernel 3: init z-buffer to FAR bits ------------------------------------
__global__ __launch_bounds__(256) void init_kernel(uint4* __restrict__ p, int n4)
{
    int i = blockIdx.x * 256 + threadIdx.x;
    if (i < n4) p[i] = make_uint4(FARBITS, FARBITS, FARBITS, FARBITS);
}

// -------- Kernel 4: triangle-parallel rasterizer (one block per triangle) --------
// zbits holds positive-float z as uint bits: atomicMin over bits == exact float min.
__global__ __launch_bounds__(256) void raster_kernel(
    const float4* __restrict__ rec, unsigned int* __restrict__ zbits, int F2)
{
#pragma clang fp contract(off)
    int t = blockIdx.x;
    int b = t / F2;
    size_t base = (size_t)t * 4;
    float4 q0 = rec[base+0];
    float4 q1 = rec[base+1];
    float4 q2 = rec[base+2];
    float4 q3 = rec[base+3];
    int c0 = __float_as_int(q3.x), c1 = __float_as_int(q3.y);
    int r0 = __float_as_int(q3.z), r1 = __float_as_int(q3.w);
    if (c1 < c0 || r1 < r0) return;
    float dens = q1.z, sgn = q1.w;
    float za = q2.x, zb = q2.y, zc = q2.z;
    unsigned int* zbuf = zbits + (size_t)b * (RASTN * RASTN);
    int tx = threadIdx.x & 15, ty = threadIdx.x >> 4;
    for (int r = r0 + ty; r <= r1; r += 16) {
        float Y = gval(r);
        float yc = Y - q0.y;
        float t0 = q0.w * yc;           // (cx-bx)*(Y-cy): identical op tree to ref
        float t1 = q1.y * yc;           // (ax-cx)*(Y-cy)
        unsigned int* rowp = zbuf + r * RASTN;
        for (int c = c0 + tx; c <= c1; c += 16) {
            float X = gval(c);
            float xc = X - q0.x;
            float e0 = (q0.z * xc) + t0;      // w0 numerator, bit-exact vs ref
            float e1 = (q1.x * xc) + t1;      // w1 numerator
            // conservative sign prefilters; exact tests inside decide
            float s2 = ((dens - e0) - e1) * sgn;
            float eps2 = 1e-5f * ((fabsf(dens) + fabsf(e0)) + fabsf(e1));
            if (e0 * sgn > -1e-30f && e1 * sgn > -1e-30f && s2 > -eps2) {
                float w0 = e0 / dens;          // IEEE div == ref
                float w1 = e1 / dens;
                float w2 = (1.0f - w0) - w1;
                float inv = ((w0 / za) + (w1 / zb)) + (w2 / zc);
                if ((w0 >= 0.0f) && (w1 >= 0.0f) && (w2 >= 0.0f) && (inv > 1e-8f)) {
                    float zp = 1.0f / inv;     // exact div == ref zp
                    atomicMin(rowp + c, __float_as_uint(zp));
                }
            }
        }
    }
}

// -------- Kernel 5: per-batch max(no_back)/min reduction -------------------------
__global__ __launch_bounds__(256) void minmax_kernel(
    const float* __restrict__ zbuf, float* __restrict__ mm, int npix)
{
    __shared__ float smx[256], smn[256];
    int b = blockIdx.x;
    const float* p = zbuf + (size_t)b * npix;
    float vmx = -3e38f, vmn = 3e38f;
    for (int i = threadIdx.x; i < npix; i += 256) {
        float z = p[i];
        float nb = (z == FARV) ? 0.0f : z;   // (1-img_inf)*img
        vmx = fmaxf(vmx, nb);
        vmn = fminf(vmn, z);
    }
    smx[threadIdx.x] = vmx; smn[threadIdx.x] = vmn;
    __syncthreads();
    for (int s = 128; s > 0; s >>= 1) {
        if (threadIdx.x < s) {
            smx[threadIdx.x] = fmaxf(smx[threadIdx.x], smx[threadIdx.x+s]);
            smn[threadIdx.x] = fminf(smn[threadIdx.x], smn[threadIdx.x+s]);
        }
        __syncthreads();
    }
    if (threadIdx.x == 0) { mm[b*2] = smx[0]; mm[b*2+1] = smn[0]; }
}

// -------- Kernel 6: normalize depth in place + write mask -------------------------
__global__ __launch_bounds__(256) void final_kernel(
    float* __restrict__ zdep, float* __restrict__ mask,
    const float* __restrict__ mm, int npix, int total)
{
#pragma clang fp contract(off)
    int idx = blockIdx.x*256 + threadIdx.x;
    if (idx >= total) return;
    int b = idx / npix;
    float mx = mm[b*2], mn = mm[b*2+1];
    float z = zdep[idx];
    // cover == any valid hit == (z < FAR): valid hits here have zp <= ~1.25 << 10
    // (w0+w1+w2 == 1 exactly, all >= 0, z-verts in (1e-8, ~1.2])
    mask[idx] = (z < FARV) ? 1.0f : 0.0f;
    float nd = (mx - z) / ((mx - mn) + 1e-4f);
    float cv = nd;
    cv = (cv < 0.0f) ? 0.0f : cv;
    cv = (cv > 1.0f) ? 1.0f : cv;
    zdep[idx] = cv;
}

extern "C" void kernel_launch(void* const* d_in, const int* in_sizes, int n_in,
                              void* d_out, int out_size, void* d_ws, size_t ws_size,
                              hipStream_t stream)
{
    const float* verts = (const float*)d_in[0];
    const int*   faces = (const int*)d_in[1];
    const float* Km    = (const float*)d_in[2];
    const float* Rm    = (const float*)d_in[3];
    const float* tm    = (const float*)d_in[4];
    const float* dm    = (const float*)d_in[5];
    float* out = (float*)d_out;

    int B  = in_sizes[2] / 9;          // intr is B*3*3
    int V  = in_sizes[0] / (3 * B);
    int F  = in_sizes[1] / (3 * B);
    int F2 = 2 * F;
    int npix = RASTN * RASTN;

    char* ws = (char*)d_ws;
    float* uvz = (float*)ws;
    size_t o_rec = (((size_t)B * V * 3 * sizeof(float)) + 255) & ~(size_t)255;
    float4* rec = (float4*)(ws + o_rec);
    size_t o_mm = ((o_rec + (size_t)B * F2 * 4 * sizeof(float4)) + 255) & ~(size_t)255;
    float* mm = (float*)(ws + o_mm);

    float* zdep = out;                       // depth region doubles as zbuf
    float* mask = out + (size_t)B * npix;

    int totV = B * V;
    proj_kernel<<<(totV + 255) / 256, 256, 0, stream>>>(verts, Km, Rm, tm, dm, uvz, totV, V);
    int totT = B * F2;
    prep_kernel<<<(totT + 255) / 256, 256, 0, stream>>>(uvz, faces, rec, totT, F2, F, V);
    int n4 = (B * npix) / 4;
    init_kernel<<<(n4 + 255) / 256, 256, 0, stream>>>((uint4*)zdep, n4);
    raster_kernel<<<totT, 256, 0, stream>>>(rec, (unsigned int*)zdep, F2);
    minmax_kernel<<<B, 256, 0, stream>>>(zdep, mm, npix);
    final_kernel<<<(B * npix + 255) / 256, 256, 0, stream>>>(zdep, mask, mm, npix, B * npix);
}

// Round 3
// 332.132 us; speedup vs baseline: 3.3264x; 2.0876x over previous
//
#include <hip/hip_runtime.h>
#include <cstdint>

#define RASTN 256
#define FARV 10.0f
#define FARBITS 0x41200000u   // bits of 10.0f

__device__ __forceinline__ float gval(int i) {
    // g = 2*(i+0.5)/256 - 1  -- exact in f32 (multiples of 1/256)
    return (2.0f * ((float)i + 0.5f)) / 256.0f - 1.0f;
}

// -------- Kernel 1: project vertices -> uvz (replicates _project bit-exactly) -----
// Also initializes the per-batch minmax accumulators (mm) used by raster's atomics.
__global__ __launch_bounds__(256) void proj_kernel(
    const float* __restrict__ verts, const float* __restrict__ Km,
    const float* __restrict__ Rm, const float* __restrict__ tm,
    const float* __restrict__ dm, float* __restrict__ uvz,
    unsigned int* __restrict__ mm, int total, int V, int B)
{
#pragma clang fp contract(off)
    int idx = blockIdx.x * blockDim.x + threadIdx.x;
    if (idx < 2*B) mm[idx] = (idx & 1) ? FARBITS : 0u;   // [max-bits=0, min-bits=FAR]
    if (idx >= total) return;
    int b = idx / V;
    const float* R = Rm + b * 9;
    const float* K = Km + b * 9;
    const float* t = tm + b * 3;
    const float* d = dm + b * 5;
    float vx = verts[(size_t)idx*3+0], vy = verts[(size_t)idx*3+1], vz = verts[(size_t)idx*3+2];
    float cxm = ((vx*R[0] + vy*R[1]) + vz*R[2]) + t[0];
    float cym = ((vx*R[3] + vy*R[4]) + vz*R[5]) + t[1];
    float czm = ((vx*R[6] + vy*R[7]) + vz*R[8]) + t[2];
    float zd = czm + 1e-9f;
    float x_ = cxm / zd;
    float y_ = cym / zd;
    float k1 = d[0], k2 = d[1], p1 = d[2], p2 = d[3], k3 = d[4];
    float r2   = (x_*x_) + (y_*y_);
    float r2_2 = r2 * r2;
    float r2_3 = r2 * r2_2;
    float radial = ((1.0f + k1*r2) + k2*r2_2) + k3*r2_3;
    float x__ = ((x_*radial) + (((2.0f*p1)*x_)*y_)) + (p2*(r2 + 2.0f*(x_*x_)));
    float y__ = ((y_*radial) + (p1*(r2 + 2.0f*(y_*y_)))) + (((2.0f*p2)*x_)*y_);
    float up = ((x__*K[0]) + (y__*K[1])) + (1.0f*K[2]);
    float vp = ((x__*K[3]) + (y__*K[4])) + (1.0f*K[5]);
    vp = 256.0f - vp;
    float un = (2.0f*(up - 128.0f)) / 256.0f;
    float vn = (2.0f*(vp - 128.0f)) / 256.0f;
    uvz[(size_t)idx*3+0] = un;
    uvz[(size_t)idx*3+1] = vn;
    uvz[(size_t)idx*3+2] = czm;
}

// -------- Kernel 2: per-triangle setup records (4x float4 each) -------------------
// q0 = (cx, cy, by-cy, cx-bx)
// q1 = (cy-ay, ax-cx, den_s, sign(den_s))
// q2 = (zs(az), zs(bz), zs(cz), 0)
// q3 = (packed int bbox [ic0|ic1<<8|ir0<<16|ir1<<24], minz*(1-4e-4), 0, 0)
//      dead -> bbox ic0=1,ic1=0 (fails ic0<=ic1), minz=3e38
__global__ __launch_bounds__(256) void prep_kernel(
    const float* __restrict__ uvz, const int* __restrict__ faces,
    float4* __restrict__ rec, int total, int F2, int F, int V)
{
#pragma clang fp contract(off)
    int idx = blockIdx.x * blockDim.x + threadIdx.x;
    if (idx >= total) return;
    int b = idx / F2;
    int j = idx - b * F2;
    const int* fb = faces + (size_t)b * F * 3;
    int i0, i1, i2;
    if (j < F) { i0 = fb[j*3+0]; i1 = fb[j*3+1]; i2 = fb[j*3+2]; }
    else { int jj = j - F; i0 = fb[jj*3+2]; i1 = fb[jj*3+1]; i2 = fb[jj*3+0]; }
    const float* ub = uvz + (size_t)b * V * 3;
    float ax = ub[i0*3+0], ay = ub[i0*3+1], az = ub[i0*3+2];
    float bx = ub[i1*3+0], by = ub[i1*3+1], bz = ub[i1*3+2];
    float cx = ub[i2*3+0], cy = ub[i2*3+1], cz = ub[i2*3+2];
    float den = (bx-ax)*(cy-ay) - (by-ay)*(cx-ax);
    bool ok = fabsf(den) > 1e-8f;
    float dens = ok ? den : 1.0f;
    bool alive = ok && (az > 1e-8f) && (bz > 1e-8f) && (cz > 1e-8f);
    float za = (az > 1e-8f) ? az : 1.0f;
    float zb = (bz > 1e-8f) ? bz : 1.0f;
    float zc = (cz > 1e-8f) ? cz : 1.0f;
    float mnx = fminf(ax, fminf(bx, cx));
    float mxx = fmaxf(ax, fmaxf(bx, cx));
    float mny = fminf(ay, fminf(by, cy));
    float mxy = fmaxf(ay, fmaxf(by, cy));
    // conservative margin (same logic that passed in R1/R2)
    float m = 1e-3f + 1e-6f*((fabsf(mnx)+fabsf(mxx))+(fabsf(mny)+fabsf(mxy)));
    mnx -= m; mxx += m; mny -= m; mxy += m;
    if (!(mxx >= -1.0f) || !(mnx <= 1.0f) || !(mxy >= -1.0f) || !(mny <= 1.0f)) alive = false;
    int ic0 = 1, ic1 = 0, ir0 = 1, ir1 = 0;   // empty
    float minz = 3e38f;
    if (alive) {
        float lx = fmaxf(mnx, -1.5f), hx = fminf(mxx, 1.5f);
        float ly = fmaxf(mny, -1.5f), hy = fminf(mxy, 1.5f);
        ic0 = (int)floorf((lx + 1.0f) * 128.0f - 0.5f);
        ic1 = (int)ceilf ((hx + 1.0f) * 128.0f - 0.5f);
        ir0 = (int)floorf((ly + 1.0f) * 128.0f - 0.5f);
        ir1 = (int)ceilf ((hy + 1.0f) * 128.0f - 0.5f);
        ic0 = ic0 < 0 ? 0 : ic0;  ir0 = ir0 < 0 ? 0 : ir0;
        ic1 = ic1 > 255 ? 255 : ic1;  ir1 = ir1 > 255 ? 255 : ir1;
        if (ic0 > ic1 || ir0 > ir1) { ic0 = 1; ic1 = 0; ir0 = 1; ir1 = 0; minz = 3e38f; }
        else minz = fminf(za, fminf(zb, zc)) * (1.0f - 4e-4f);  // conservative early-z key
    }
    int pack = ic0 | (ic1 << 8) | (ir0 << 16) | (ir1 << 24);
    size_t base = (size_t)idx * 4;
    rec[base+0] = make_float4(cx, cy, by - cy, cx - bx);
    rec[base+1] = make_float4(cy - ay, ax - cx, dens, dens > 0.0f ? 1.0f : -1.0f);
    rec[base+2] = make_float4(za, zb, zc, 0.0f);
    rec[base+3] = make_float4(__int_as_float(pack), minz, 0.0f, 0.0f);
}

// -------- Kernel 3: bin triangles per 16x16 tile (one block per tile) ------------
// bins[(b*256+tile)*F2 + k] = triangle index (ascending, deterministic); bcnt = count
__global__ __launch_bounds__(256) void bin_kernel(
    const float4* __restrict__ rec, unsigned short* __restrict__ bins,
    int* __restrict__ bcnt, int F2)
{
    int tile = blockIdx.x, b = blockIdx.y;
    int tc = tile & 15, tr = tile >> 4;
    int pc0 = tc*16, pc1 = pc0+15, pr0 = tr*16, pr1 = pr0+15;
    const float4* rb = rec + (size_t)b * F2 * 4;
    unsigned short* tb = bins + (size_t)(b*256 + tile) * F2;
    __shared__ int s_wcnt[4], s_woff[4], s_base;
    int tid = threadIdx.x, lane = tid & 63, wv = tid >> 6;
    if (tid == 0) s_base = 0;
    __syncthreads();
    int nch = (F2 + 255) / 256;
    for (int c = 0; c < nch; ++c) {
        int t = c*256 + tid;
        bool k = false;
        if (t < F2) {
            float4 q3 = rb[(size_t)t*4+3];
            int pk = __float_as_int(q3.x);
            int ic0 = pk & 255, ic1 = (pk >> 8) & 255;
            int ir0 = (pk >> 16) & 255, ir1 = (pk >> 24) & 255;
            k = (ic0 <= ic1) && (ic0 <= pc1) && (ic1 >= pc0) && (ir0 <= pr1) && (ir1 >= pr0);
        }
        unsigned long long bm = __ballot(k ? 1 : 0);
        int wcnt = __popcll(bm);
        int pfx = __popcll(bm & ((1ull << lane) - 1ull));
        if (lane == 0) s_wcnt[wv] = wcnt;
        __syncthreads();
        if (tid == 0) {
            int acc = s_base;
            for (int q = 0; q < 4; ++q) { s_woff[q] = acc; acc += s_wcnt[q]; }
            s_base = acc;
        }
        __syncthreads();
        if (k) tb[s_woff[wv] + pfx] = (unsigned short)t;
        __syncthreads();
    }
    if (tid == 0) bcnt[b*256 + tile] = s_base;
}

// -------- Kernel 4: tile raster, register z-buffer, early-z, no atomics on zbuf --
__global__ __launch_bounds__(256) void raster_kernel(
    const float4* __restrict__ rec, const unsigned short* __restrict__ bins,
    const int* __restrict__ bcnt, float* __restrict__ zdep,
    unsigned int* __restrict__ mm, int F2)
{
#pragma clang fp contract(off)
    __shared__ float4 sh[64*4];
    __shared__ int s_list[64];
    __shared__ int s_cnt;
    __shared__ float s_tzmax;
    __shared__ float s_wzx[4], s_wmx[4], s_wmn[4];
    int b = blockIdx.z;
    int tc = blockIdx.x, tr = blockIdx.y;
    int tid = threadIdx.x, lane = tid & 63, wv = tid >> 6;
    int tx = tid & 15, ty = tid >> 4;
    int col = tc*16 + tx, row = tr*16 + ty;
    float X = gval(col), Y = gval(row);
    const float4* rb = rec + (size_t)b * F2 * 4;
    int tile = tr*16 + tc;
    const unsigned short* tb = bins + (size_t)(b*256 + tile) * F2;
    int cnt = bcnt[b*256 + tile];
    float zmin = FARV;
    if (tid == 0) s_tzmax = FARV;
    __syncthreads();
    for (int base = 0; base < cnt; base += 64) {
        // wave 0: compact this 64-chunk by the tile-level early-z bound
        if (wv == 0) {
            int idx = base + lane;
            bool k = false; int tri = 0;
            if (idx < cnt) {
                tri = tb[idx];
                float mz = rb[(size_t)tri*4+3].y;
                k = (mz <= s_tzmax);
            }
            unsigned long long bm = __ballot(k ? 1 : 0);
            int pfx = __popcll(bm & ((1ull << lane) - 1ull));
            if (k) s_list[pfx] = tri;
            if (lane == 0) s_cnt = __popcll(bm);
        }
        __syncthreads();
        int n = s_cnt;
        if (tid < n*4) {
            int tri = s_list[tid >> 2];
            sh[tid] = rb[(size_t)tri*4 + (tid & 3)];
        }
        __syncthreads();
        for (int i = 0; i < n; ++i) {
            float4 q3 = sh[i*4+3];                 // broadcast read
            if (q3.y > zmin) continue;             // per-pixel early-z (conservative)
            int pk = __float_as_int(q3.x);
            int ic0 = pk & 255, ic1 = (pk >> 8) & 255;
            int ir0 = (pk >> 16) & 255, ir1 = (pk >> 24) & 255;
            if (col < ic0 || col > ic1 || row < ir0 || row > ir1) continue;
            float4 q0 = sh[i*4+0];
            float4 q1 = sh[i*4+1];
            float xc = X - q0.x;
            float yc = Y - q0.y;
            float e0 = (q0.z*xc) + (q0.w*yc);      // w0 numerator, bit-exact vs ref
            float e1 = (q1.x*xc) + (q1.y*yc);      // w1 numerator
            float dens = q1.z, sgn = q1.w;
            float s2 = ((dens - e0) - e1) * sgn;
            float eps2 = 1e-5f * ((fabsf(dens) + fabsf(e0)) + fabsf(e1));
            if (e0*sgn > -1e-30f && e1*sgn > -1e-30f && s2 > -eps2) {
                float4 q2 = sh[i*4+2];
                float w0 = e0 / dens;              // IEEE div == ref
                float w1 = e1 / dens;
                float w2 = (1.0f - w0) - w1;
                float inv = ((w0 / q2.x) + (w1 / q2.y)) + (w2 / q2.z);
                if ((w0 >= 0.0f) && (w1 >= 0.0f) && (w2 >= 0.0f) && (inv > 1e-8f)) {
                    float zp = 1.0f / inv;         // exact div == ref zp
                    zmin = fminf(zmin, zp);
                }
            }
        }
        // refresh conservative tile-wide zmax (only shrinks -> stays conservative)
        float zx = zmin;
        for (int o = 32; o; o >>= 1) zx = fmaxf(zx, __shfl_xor(zx, o));
        if (lane == 0) s_wzx[wv] = zx;
        __syncthreads();
        if (tid == 0) s_tzmax = fmaxf(fmaxf(s_wzx[0], s_wzx[1]), fmaxf(s_wzx[2], s_wzx[3]));
        __syncthreads();
    }
    size_t pix = ((size_t)b*RASTN + row)*RASTN + col;
    zdep[pix] = zmin;
    // fused per-batch minmax: block-reduce then one atomic pair per block
    float nb = (zmin == FARV) ? 0.0f : zmin;      // (1-img_inf)*img
    float a = nb, mn = zmin;
    for (int o = 32; o; o >>= 1) {
        a  = fmaxf(a,  __shfl_xor(a,  o));
        mn = fminf(mn, __shfl_xor(mn, o));
    }
    if (lane == 0) { s_wmx[wv] = a; s_wmn[wv] = mn; }
    __syncthreads();
    if (tid == 0) {
        float bmx = fmaxf(fmaxf(s_wmx[0], s_wmx[1]), fmaxf(s_wmx[2], s_wmx[3]));
        float bmn = fminf(fminf(s_wmn[0], s_wmn[1]), fminf(s_wmn[2], s_wmn[3]));
        atomicMax(mm + 2*b,     __float_as_uint(bmx));   // positive floats: bit-monotone
        atomicMin(mm + 2*b + 1, __float_as_uint(bmn));
    }
}

// -------- Kernel 5: normalize depth in place + write mask -------------------------
__global__ __launch_bounds__(256) void final_kernel(
    float* __restrict__ zdep, float* __restrict__ mask,
    const unsigned int* __restrict__ mm, int npix, int total)
{
#pragma clang fp contract(off)
    int idx = blockIdx.x*256 + threadIdx.x;
    if (idx >= total) return;
    int b = idx / npix;
    float mx = __uint_as_float(mm[2*b]);
    float mn = __uint_as_float(mm[2*b + 1]);
    float z = zdep[idx];
    // cover == any valid hit == (z < FAR): valid hits have zp <= ~1.25 << 10
    mask[idx] = (z < FARV) ? 1.0f : 0.0f;
    float nd = (mx - z) / ((mx - mn) + 1e-4f);
    float cv = nd;
    cv = (cv < 0.0f) ? 0.0f : cv;
    cv = (cv > 1.0f) ? 1.0f : cv;
    zdep[idx] = cv;
}

extern "C" void kernel_launch(void* const* d_in, const int* in_sizes, int n_in,
                              void* d_out, int out_size, void* d_ws, size_t ws_size,
                              hipStream_t stream)
{
    const float* verts = (const float*)d_in[0];
    const int*   faces = (const int*)d_in[1];
    const float* Km    = (const float*)d_in[2];
    const float* Rm    = (const float*)d_in[3];
    const float* tm    = (const float*)d_in[4];
    const float* dm    = (const float*)d_in[5];
    float* out = (float*)d_out;

    int B  = in_sizes[2] / 9;          // intr is B*3*3
    int V  = in_sizes[0] / (3 * B);
    int F  = in_sizes[1] / (3 * B);
    int F2 = 2 * F;
    int npix = RASTN * RASTN;

    char* ws = (char*)d_ws;
    size_t off = 0;
    float* uvz = (float*)(ws + off);
    off = (off + (size_t)B * V * 3 * sizeof(float) + 255) & ~(size_t)255;
    float4* rec = (float4*)(ws + off);
    off = (off + (size_t)B * F2 * 4 * sizeof(float4) + 255) & ~(size_t)255;
    unsigned short* bins = (unsigned short*)(ws + off);
    off = (off + (size_t)B * 256 * F2 * sizeof(unsigned short) + 255) & ~(size_t)255;
    int* bcnt = (int*)(ws + off);
    off = (off + (size_t)B * 256 * sizeof(int) + 255) & ~(size_t)255;
    unsigned int* mm = (unsigned int*)(ws + off);

    float* zdep = out;                       // depth region doubles as zbuf
    float* mask = out + (size_t)B * npix;

    int totV = B * V;
    proj_kernel<<<(totV + 255) / 256, 256, 0, stream>>>(verts, Km, Rm, tm, dm, uvz, mm, totV, V, B);
    int totT = B * F2;
    prep_kernel<<<(totT + 255) / 256, 256, 0, stream>>>(uvz, faces, rec, totT, F2, F, V);
    dim3 bgrid(256, B);
    bin_kernel<<<bgrid, 256, 0, stream>>>(rec, bins, bcnt, F2);
    dim3 rgrid(16, 16, B), rblk(256);
    raster_kernel<<<rgrid, rblk, 0, stream>>>(rec, bins, bcnt, zdep, mm, F2);
    final_kernel<<<(B * npix + 255) / 256, 256, 0, stream>>>(zdep, mask, mm, npix, B * npix);
}

// Round 4
// 273.453 us; speedup vs baseline: 4.0401x; 1.2146x over previous
//
#include <hip/hip_runtime.h>
#include <cstdint>

#define RASTN 256
#define FARV 10.0f
#define FARBITS 0x41200000u   // bits of 10.0f
#define SPLIT 4
#define SORTN 4096            // power of two >= F2 (F2 = 3076)

__device__ __forceinline__ float gval(int i) {
    // g = 2*(i+0.5)/256 - 1  -- exact in f32 (multiples of 1/256)
    return (2.0f * ((float)i + 0.5f)) / 256.0f - 1.0f;
}

// -------- Kernel 1: project vertices -> uvz (replicates _project bit-exactly) -----
// Also initializes the per-batch minmax accumulators (mm).
__global__ __launch_bounds__(256) void proj_kernel(
    const float* __restrict__ verts, const float* __restrict__ Km,
    const float* __restrict__ Rm, const float* __restrict__ tm,
    const float* __restrict__ dm, float* __restrict__ uvz,
    unsigned int* __restrict__ mm, int total, int V, int B)
{
#pragma clang fp contract(off)
    int idx = blockIdx.x * blockDim.x + threadIdx.x;
    if (idx < 2*B) mm[idx] = (idx & 1) ? FARBITS : 0u;   // [max-bits=0, min-bits=FAR]
    if (idx >= total) return;
    int b = idx / V;
    const float* R = Rm + b * 9;
    const float* K = Km + b * 9;
    const float* t = tm + b * 3;
    const float* d = dm + b * 5;
    float vx = verts[(size_t)idx*3+0], vy = verts[(size_t)idx*3+1], vz = verts[(size_t)idx*3+2];
    float cxm = ((vx*R[0] + vy*R[1]) + vz*R[2]) + t[0];
    float cym = ((vx*R[3] + vy*R[4]) + vz*R[5]) + t[1];
    float czm = ((vx*R[6] + vy*R[7]) + vz*R[8]) + t[2];
    float zd = czm + 1e-9f;
    float x_ = cxm / zd;
    float y_ = cym / zd;
    float k1 = d[0], k2 = d[1], p1 = d[2], p2 = d[3], k3 = d[4];
    float r2   = (x_*x_) + (y_*y_);
    float r2_2 = r2 * r2;
    float r2_3 = r2 * r2_2;
    float radial = ((1.0f + k1*r2) + k2*r2_2) + k3*r2_3;
    float x__ = ((x_*radial) + (((2.0f*p1)*x_)*y_)) + (p2*(r2 + 2.0f*(x_*x_)));
    float y__ = ((y_*radial) + (p1*(r2 + 2.0f*(y_*y_)))) + (((2.0f*p2)*x_)*y_);
    float up = ((x__*K[0]) + (y__*K[1])) + (1.0f*K[2]);
    float vp = ((x__*K[3]) + (y__*K[4])) + (1.0f*K[5]);
    vp = 256.0f - vp;
    float un = (2.0f*(up - 128.0f)) / 256.0f;
    float vn = (2.0f*(vp - 128.0f)) / 256.0f;
    uvz[(size_t)idx*3+0] = un;
    uvz[(size_t)idx*3+1] = vn;
    uvz[(size_t)idx*3+2] = czm;
}

// -------- Kernel 2: per-triangle setup records --------------------------------
// rec q0 = (cx, cy, by-cy, cx-bx)
//     q1 = (cy-ay, ax-cx, den_s, sign(den_s))
//     q2 = (zs(az), zs(bz), zs(cz), 0)
//     q3 = (packed bbox bits, minz*(1-4e-4), 0, 0)
// aux[idx] = (packed bbox, minz bits)   for binning / sort / early-z gathers
__global__ __launch_bounds__(256) void prep_kernel(
    const float* __restrict__ uvz, const int* __restrict__ faces,
    float4* __restrict__ rec, uint2* __restrict__ aux,
    int total, int F2, int F, int V)
{
#pragma clang fp contract(off)
    int idx = blockIdx.x * blockDim.x + threadIdx.x;
    if (idx >= total) return;
    int b = idx / F2;
    int j = idx - b * F2;
    const int* fb = faces + (size_t)b * F * 3;
    int i0, i1, i2;
    if (j < F) { i0 = fb[j*3+0]; i1 = fb[j*3+1]; i2 = fb[j*3+2]; }
    else { int jj = j - F; i0 = fb[jj*3+2]; i1 = fb[jj*3+1]; i2 = fb[jj*3+0]; }
    const float* ub = uvz + (size_t)b * V * 3;
    float ax = ub[i0*3+0], ay = ub[i0*3+1], az = ub[i0*3+2];
    float bx = ub[i1*3+0], by = ub[i1*3+1], bz = ub[i1*3+2];
    float cx = ub[i2*3+0], cy = ub[i2*3+1], cz = ub[i2*3+2];
    float den = (bx-ax)*(cy-ay) - (by-ay)*(cx-ax);
    bool ok = fabsf(den) > 1e-8f;
    float dens = ok ? den : 1.0f;
    bool alive = ok && (az > 1e-8f) && (bz > 1e-8f) && (cz > 1e-8f);
    float za = (az > 1e-8f) ? az : 1.0f;
    float zb = (bz > 1e-8f) ? bz : 1.0f;
    float zc = (cz > 1e-8f) ? cz : 1.0f;
    float mnx = fminf(ax, fminf(bx, cx));
    float mxx = fmaxf(ax, fmaxf(bx, cx));
    float mny = fminf(ay, fminf(by, cy));
    float mxy = fmaxf(ay, fmaxf(by, cy));
    // conservative margin (same logic that passed R1-R3)
    float m = 1e-3f + 1e-6f*((fabsf(mnx)+fabsf(mxx))+(fabsf(mny)+fabsf(mxy)));
    mnx -= m; mxx += m; mny -= m; mxy += m;
    if (!(mxx >= -1.0f) || !(mnx <= 1.0f) || !(mxy >= -1.0f) || !(mny <= 1.0f)) alive = false;
    int ic0 = 1, ic1 = 0, ir0 = 1, ir1 = 0;   // empty
    float minz = 3e38f;
    if (alive) {
        float lx = fmaxf(mnx, -1.5f), hx = fminf(mxx, 1.5f);
        float ly = fmaxf(mny, -1.5f), hy = fminf(mxy, 1.5f);
        ic0 = (int)floorf((lx + 1.0f) * 128.0f - 0.5f);
        ic1 = (int)ceilf ((hx + 1.0f) * 128.0f - 0.5f);
        ir0 = (int)floorf((ly + 1.0f) * 128.0f - 0.5f);
        ir1 = (int)ceilf ((hy + 1.0f) * 128.0f - 0.5f);
        ic0 = ic0 < 0 ? 0 : ic0;  ir0 = ir0 < 0 ? 0 : ir0;
        ic1 = ic1 > 255 ? 255 : ic1;  ir1 = ir1 > 255 ? 255 : ir1;
        if (ic0 > ic1 || ir0 > ir1) { ic0 = 1; ic1 = 0; ir0 = 1; ir1 = 0; minz = 3e38f; }
        else minz = fminf(za, fminf(zb, zc)) * (1.0f - 4e-4f);  // conservative early-z key
    }
    int pack = ic0 | (ic1 << 8) | (ir0 << 16) | (ir1 << 24);
    size_t base = (size_t)idx * 4;
    rec[base+0] = make_float4(cx, cy, by - cy, cx - bx);
    rec[base+1] = make_float4(cy - ay, ax - cx, dens, dens > 0.0f ? 1.0f : -1.0f);
    rec[base+2] = make_float4(za, zb, zc, 0.0f);
    rec[base+3] = make_float4(__int_as_float(pack), minz, 0.0f, 0.0f);
    aux[idx] = make_uint2((unsigned int)pack, __float_as_uint(minz));
}

// -------- Kernel 3: per-batch bitonic sort by minz (ascending) -------------------
// sidx[b][s] = triangle index in ascending-minz order. Positive-float bits are
// order-isomorphic, so uint compare == float compare. Deterministic via idx tiebreak.
__global__ __launch_bounds__(1024) void sort_kernel(
    const uint2* __restrict__ aux, int* __restrict__ sidx, int F2)
{
    __shared__ unsigned long long sk[SORTN];
    int b = blockIdx.x, tid = threadIdx.x;
    const uint2* ab = aux + (size_t)b * F2;
    int* sb = sidx + (size_t)b * SORTN;
    if (F2 > SORTN) {                     // fallback: identity (raster won't break)
        for (int i = tid; i < F2; i += 1024) sb[i] = i;
        return;
    }
    for (int i = tid; i < SORTN; i += 1024)
        sk[i] = (i < F2) ? ((((unsigned long long)ab[i].y) << 32) | (unsigned int)i)
                         : ~0ull;
    __syncthreads();
    for (int k2 = 2; k2 <= SORTN; k2 <<= 1) {
        for (int j = k2 >> 1; j > 0; j >>= 1) {
            for (int i = tid; i < SORTN; i += 1024) {
                int l = i ^ j;
                if (l > i) {
                    bool asc = (i & k2) == 0;
                    unsigned long long a = sk[i], c = sk[l];
                    if ((a > c) == asc) { sk[i] = c; sk[l] = a; }
                }
            }
            __syncthreads();
        }
    }
    for (int i = tid; i < F2; i += 1024) sb[i] = (int)(sk[i] & 0xffffffffu);
}

// -------- Kernel 4: bin triangles per 16x16 tile, in sorted (minz asc) order -----
__global__ __launch_bounds__(256) void bin_kernel(
    const uint2* __restrict__ aux, const int* __restrict__ sidx,
    unsigned short* __restrict__ bins, int* __restrict__ bcnt, int F2)
{
    int tile = blockIdx.x, b = blockIdx.y;
    int tc = tile & 15, tr = tile >> 4;
    int pc0 = tc*16, pc1 = pc0+15, pr0 = tr*16, pr1 = pr0+15;
    const uint2* ab = aux + (size_t)b * F2;
    const int* sb = sidx + (size_t)b * SORTN;
    unsigned short* tb = bins + (size_t)(b*256 + tile) * F2;
    __shared__ int s_wcnt[4], s_woff[4], s_base;
    int tid = threadIdx.x, lane = tid & 63, wv = tid >> 6;
    if (tid == 0) s_base = 0;
    __syncthreads();
    int nch = (F2 + 255) / 256;
    for (int c = 0; c < nch; ++c) {
        int s = c*256 + tid;
        bool k = false; int t = 0;
        if (s < F2) {
            t = sb[s];
            int pk = (int)ab[t].x;
            int ic0 = pk & 255, ic1 = (pk >> 8) & 255;
            int ir0 = (pk >> 16) & 255, ir1 = (pk >> 24) & 255;
            k = (ic0 <= ic1) && (ic0 <= pc1) && (ic1 >= pc0) && (ir0 <= pr1) && (ir1 >= pr0);
        }
        unsigned long long bm = __ballot(k ? 1 : 0);
        int wcnt = __popcll(bm);
        int pfx = __popcll(bm & ((1ull << lane) - 1ull));
        if (lane == 0) s_wcnt[wv] = wcnt;
        __syncthreads();
        if (tid == 0) {
            int acc = s_base;
            for (int q = 0; q < 4; ++q) { s_woff[q] = acc; acc += s_wcnt[q]; }
            s_base = acc;
        }
        __syncthreads();
        if (k) tb[s_woff[wv] + pfx] = (unsigned short)t;
        __syncthreads();
    }
    if (tid == 0) bcnt[b*256 + tile] = s_base;
}

// -------- Kernel 5: init z-buffer to FAR bits ------------------------------------
__global__ __launch_bounds__(256) void init_kernel(uint4* __restrict__ p, int n4)
{
    int i = blockIdx.x * 256 + threadIdx.x;
    if (i < n4) p[i] = make_uint4(FARBITS, FARBITS, FARBITS, FARBITS);
}

// -------- Kernel 6: tile raster. SPLIT blocks/tile, sorted bins, early-z + break -
__global__ __launch_bounds__(256) void raster_kernel(
    const float4* __restrict__ rec, const uint2* __restrict__ aux,
    const unsigned short* __restrict__ bins, const int* __restrict__ bcnt,
    unsigned int* __restrict__ zbits, int F2, int sortedFlag)
{
#pragma clang fp contract(off)
    __shared__ float4 sh[64*4];
    __shared__ int s_list[64];
    __shared__ int s_cnt;
    __shared__ float s_tzmax;
    __shared__ float s_wzx[4];
    int zz = blockIdx.z;
    int b = zz / SPLIT, sp = zz - b * SPLIT;
    int tc = blockIdx.x, tr = blockIdx.y;
    int tid = threadIdx.x, lane = tid & 63, wv = tid >> 6;
    int tx = tid & 15, ty = tid >> 4;
    int col = tc*16 + tx, row = tr*16 + ty;
    float X = gval(col), Y = gval(row);
    const float4* rb = rec + (size_t)b * F2 * 4;
    const uint2* ab = aux + (size_t)b * F2;
    int tile = tr*16 + tc;
    const unsigned short* tb = bins + (size_t)(b*256 + tile) * F2;
    int cnt = bcnt[b*256 + tile];
    int m = (cnt > sp) ? ((cnt - sp + SPLIT - 1) / SPLIT) : 0;   // my subsequence length
    float zmin = FARV;
    if (tid == 0) s_tzmax = FARV;
    __syncthreads();
    for (int base = 0; base < m; base += 64) {
        // wave 0: compact this 64-chunk of my (ascending-minz) subsequence by early-z
        if (wv == 0) {
            int i = base + lane;
            bool k = false; int tri = 0;
            if (i < m) {
                tri = tb[sp + i*SPLIT];
                float mz = __uint_as_float(ab[tri].y);
                k = (mz <= s_tzmax);
            }
            unsigned long long bm = __ballot(k ? 1 : 0);
            int pfx = __popcll(bm & ((1ull << lane) - 1ull));
            if (k) s_list[pfx] = tri;
            if (lane == 0) s_cnt = __popcll(bm);
        }
        __syncthreads();
        int n = s_cnt;                      // uniform across block
        if (n == 0) {
            // sorted: all remaining minz >= this chunk's minz > tzmax -> done
            if (sortedFlag) break; else continue;
        }
        if (tid < n*4) {
            int tri = s_list[tid >> 2];
            sh[tid] = rb[(size_t)tri*4 + (tid & 3)];
        }
        __syncthreads();
        for (int i = 0; i < n; ++i) {
            float4 q3 = sh[i*4+3];                 // broadcast read
            if (q3.y > zmin) continue;             // per-pixel early-z (conservative)
            int pk = __float_as_int(q3.x);
            int ic0 = pk & 255, ic1 = (pk >> 8) & 255;
            int ir0 = (pk >> 16) & 255, ir1 = (pk >> 24) & 255;
            if (col < ic0 || col > ic1 || row < ir0 || row > ir1) continue;
            float4 q0 = sh[i*4+0];
            float4 q1 = sh[i*4+1];
            float xc = X - q0.x;
            float yc = Y - q0.y;
            float e0 = (q0.z*xc) + (q0.w*yc);      // w0 numerator, bit-exact vs ref
            float e1 = (q1.x*xc) + (q1.y*yc);      // w1 numerator
            float dens = q1.z, sgn = q1.w;
            float s2 = ((dens - e0) - e1) * sgn;
            float eps2 = 1e-5f * ((fabsf(dens) + fabsf(e0)) + fabsf(e1));
            if (e0*sgn > -1e-30f && e1*sgn > -1e-30f && s2 > -eps2) {
                float4 q2 = sh[i*4+2];
                float w0 = e0 / dens;              // IEEE div == ref
                float w1 = e1 / dens;
                float w2 = (1.0f - w0) - w1;
                float inv = ((w0 / q2.x) + (w1 / q2.y)) + (w2 / q2.z);
                if ((w0 >= 0.0f) && (w1 >= 0.0f) && (w2 >= 0.0f) && (inv > 1e-8f)) {
                    float zp = 1.0f / inv;         // exact div == ref zp
                    zmin = fminf(zmin, zp);
                }
            }
        }
        // refresh conservative tile-wide zmax (only shrinks -> stays conservative)
        float zx = zmin;
        for (int o = 32; o; o >>= 1) zx = fmaxf(zx, __shfl_xor(zx, o));
        if (lane == 0) s_wzx[wv] = zx;
        __syncthreads();
        if (tid == 0) s_tzmax = fmaxf(fmaxf(s_wzx[0], s_wzx[1]), fmaxf(s_wzx[2], s_wzx[3]));
        __syncthreads();
    }
    if (zmin < FARV) {
        size_t pix = ((size_t)b*RASTN + row)*RASTN + col;
        atomicMin(zbits + pix, __float_as_uint(zmin));   // positive floats: bit-monotone
    }
}

// -------- Kernel 7: per-batch max(no_back)/min reduction -------------------------
__global__ __launch_bounds__(256) void minmax_kernel(
    const float* __restrict__ zbuf, unsigned int* __restrict__ mm, int seg)
{
    __shared__ float smx[4], smn[4];
    int b = blockIdx.y;
    const float* p = zbuf + (size_t)b * (RASTN*RASTN) + (size_t)blockIdx.x * seg;
    int lane = threadIdx.x & 63, wv = threadIdx.x >> 6;
    float vmx = 0.0f, vmn = FARV;
    for (int i = threadIdx.x; i < seg; i += 256) {
        float z = p[i];
        float nb = (z == FARV) ? 0.0f : z;   // (1-img_inf)*img
        vmx = fmaxf(vmx, nb);
        vmn = fminf(vmn, z);
    }
    for (int o = 32; o; o >>= 1) {
        vmx = fmaxf(vmx, __shfl_xor(vmx, o));
        vmn = fminf(vmn, __shfl_xor(vmn, o));
    }
    if (lane == 0) { smx[wv] = vmx; smn[wv] = vmn; }
    __syncthreads();
    if (threadIdx.x == 0) {
        float bmx = fmaxf(fmaxf(smx[0], smx[1]), fmaxf(smx[2], smx[3]));
        float bmn = fminf(fminf(smn[0], smn[1]), fminf(smn[2], smn[3]));
        atomicMax(mm + 2*b,     __float_as_uint(bmx));
        atomicMin(mm + 2*b + 1, __float_as_uint(bmn));
    }
}

// -------- Kernel 8: normalize depth in place + write mask -------------------------
__global__ __launch_bounds__(256) void final_kernel(
    float* __restrict__ zdep, float* __restrict__ mask,
    const unsigned int* __restrict__ mm, int npix, int total)
{
#pragma clang fp contract(off)
    int idx = blockIdx.x*256 + threadIdx.x;
    if (idx >= total) return;
    int b = idx / npix;
    float mx = __uint_as_float(mm[2*b]);
    float mn = __uint_as_float(mm[2*b + 1]);
    float z = zdep[idx];
    // cover == any valid hit == (z < FAR): valid hits have zp <= ~1.25 << 10
    mask[idx] = (z < FARV) ? 1.0f : 0.0f;
    float nd = (mx - z) / ((mx - mn) + 1e-4f);
    float cv = nd;
    cv = (cv < 0.0f) ? 0.0f : cv;
    cv = (cv > 1.0f) ? 1.0f : cv;
    zdep[idx] = cv;
}

extern "C" void kernel_launch(void* const* d_in, const int* in_sizes, int n_in,
                              void* d_out, int out_size, void* d_ws, size_t ws_size,
                              hipStream_t stream)
{
    const float* verts = (const float*)d_in[0];
    const int*   faces = (const int*)d_in[1];
    const float* Km    = (const float*)d_in[2];
    const float* Rm    = (const float*)d_in[3];
    const float* tm    = (const float*)d_in[4];
    const float* dm    = (const float*)d_in[5];
    float* out = (float*)d_out;

    int B  = in_sizes[2] / 9;          // intr is B*3*3
    int V  = in_sizes[0] / (3 * B);
    int F  = in_sizes[1] / (3 * B);
    int F2 = 2 * F;
    int npix = RASTN * RASTN;
    int sortedFlag = (F2 <= SORTN) ? 1 : 0;

    char* ws = (char*)d_ws;
    size_t off = 0;
    float* uvz = (float*)(ws + off);
    off = (off + (size_t)B * V * 3 * sizeof(float) + 255) & ~(size_t)255;
    float4* rec = (float4*)(ws + off);
    off = (off + (size_t)B * F2 * 4 * sizeof(float4) + 255) & ~(size_t)255;
    uint2* aux = (uint2*)(ws + off);
    off = (off + (size_t)B * F2 * sizeof(uint2) + 255) & ~(size_t)255;
    int* sidx = (int*)(ws + off);
    size_t sortCap = (size_t)B * ((F2 > SORTN) ? (size_t)F2 : (size_t)SORTN);
    off = (off + sortCap * sizeof(int) + 255) & ~(size_t)255;
    unsigned short* bins = (unsigned short*)(ws + off);
    off = (off + (size_t)B * 256 * F2 * sizeof(unsigned short) + 255) & ~(size_t)255;
    int* bcnt = (int*)(ws + off);
    off = (off + (size_t)B * 256 * sizeof(int) + 255) & ~(size_t)255;
    unsigned int* mm = (unsigned int*)(ws + off);

    float* zdep = out;                       // depth region doubles as zbuf
    float* mask = out + (size_t)B * npix;

    int totV = B * V;
    proj_kernel<<<(totV + 255) / 256, 256, 0, stream>>>(verts, Km, Rm, tm, dm, uvz, mm, totV, V, B);
    int totT = B * F2;
    prep_kernel<<<(totT + 255) / 256, 256, 0, stream>>>(uvz, faces, rec, aux, totT, F2, F, V);
    sort_kernel<<<B, 1024, 0, stream>>>(aux, sidx, F2);
    dim3 bgrid(256, B);
    bin_kernel<<<bgrid, 256, 0, stream>>>(aux, sidx, bins, bcnt, F2);
    int n4 = (B * npix) / 4;
    init_kernel<<<(n4 + 255) / 256, 256, 0, stream>>>((uint4*)zdep, n4);
    dim3 rgrid(16, 16, B * SPLIT);
    raster_kernel<<<rgrid, 256, 0, stream>>>(rec, aux, bins, bcnt, (unsigned int*)zdep, F2, sortedFlag);
    int seg = npix / 16;
    dim3 mgrid(16, B);
    minmax_kernel<<<mgrid, 256, 0, stream>>>(zdep, mm, seg);
    final_kernel<<<(B * npix + 255) / 256, 256, 0, stream>>>(zdep, mask, mm, npix, B * npix);
}

// Round 5
// 244.870 us; speedup vs baseline: 4.5117x; 1.1167x over previous
//
#include <hip/hip_runtime.h>
#include <cstdint>

#define RASTN 256
#define FARV 10.0f
#define FARBITS 0x41200000u   // bits of 10.0f
#define SPLIT 4
#define SORTN 4096            // power of two >= F2 (F2 = 3076)
#define PADKEY 0x7F7FF000u    // finite huge float, > any real minz key
#define EMPTYPACK 0x00010001u // ic0=1,ic1=0 -> fails overlap everywhere

__device__ __forceinline__ float gval(int i) {
    // g = 2*(i+0.5)/256 - 1  -- exact in f32 (multiples of 1/256)
    return (2.0f * ((float)i + 0.5f)) / 256.0f - 1.0f;
}

// -------- Kernel 1: project vertices -> uvz, init zbuf to FAR, init mm -----------
__global__ __launch_bounds__(256) void proj_init_kernel(
    const float* __restrict__ verts, const float* __restrict__ Km,
    const float* __restrict__ Rm, const float* __restrict__ tm,
    const float* __restrict__ dm, float* __restrict__ uvz,
    unsigned int* __restrict__ mm, uint4* __restrict__ zb4,
    int totV, int V, int B, int n4)
{
#pragma clang fp contract(off)
    int idx = blockIdx.x * blockDim.x + threadIdx.x;
    if (idx < 2*B) mm[idx] = (idx & 1) ? FARBITS : 0u;   // [max-bits=0, min-bits=FAR]
    if (idx < n4) zb4[idx] = make_uint4(FARBITS, FARBITS, FARBITS, FARBITS);
    if (idx >= totV) return;
    int b = idx / V;
    const float* R = Rm + b * 9;
    const float* K = Km + b * 9;
    const float* t = tm + b * 3;
    const float* d = dm + b * 5;
    float vx = verts[(size_t)idx*3+0], vy = verts[(size_t)idx*3+1], vz = verts[(size_t)idx*3+2];
    float cxm = ((vx*R[0] + vy*R[1]) + vz*R[2]) + t[0];
    float cym = ((vx*R[3] + vy*R[4]) + vz*R[5]) + t[1];
    float czm = ((vx*R[6] + vy*R[7]) + vz*R[8]) + t[2];
    float zd = czm + 1e-9f;
    float x_ = cxm / zd;
    float y_ = cym / zd;
    float k1 = d[0], k2 = d[1], p1 = d[2], p2 = d[3], k3 = d[4];
    float r2   = (x_*x_) + (y_*y_);
    float r2_2 = r2 * r2;
    float r2_3 = r2 * r2_2;
    float radial = ((1.0f + k1*r2) + k2*r2_2) + k3*r2_3;
    float x__ = ((x_*radial) + (((2.0f*p1)*x_)*y_)) + (p2*(r2 + 2.0f*(x_*x_)));
    float y__ = ((y_*radial) + (p1*(r2 + 2.0f*(y_*y_)))) + (((2.0f*p2)*x_)*y_);
    float up = ((x__*K[0]) + (y__*K[1])) + (1.0f*K[2]);
    float vp = ((x__*K[3]) + (y__*K[4])) + (1.0f*K[5]);
    vp = 256.0f - vp;
    float un = (2.0f*(up - 128.0f)) / 256.0f;
    float vn = (2.0f*(vp - 128.0f)) / 256.0f;
    uvz[(size_t)idx*3+0] = un;
    uvz[(size_t)idx*3+1] = vn;
    uvz[(size_t)idx*3+2] = czm;
}

// -------- Kernel 2: per-triangle setup + in-LDS 32-bit-key bitonic sort ----------
// rec q0 = (cx, cy, by-cy, cx-bx)
//     q1 = (cy-ay, ax-cx, rcp(dens), rcp(za))      [rcp approx, filter-only]
//     q2 = (dens, za, zb, zc)                      [exact path]
//     q3 = (pack bbox bits, minz*(1-4e-4), rcp(zb), rcp(zc))
// saux[rank] = (pack, minz-key20 bits); stri[rank] = triangle index.
__global__ __launch_bounds__(1024) void prep_sort_kernel(
    const float* __restrict__ uvz, const int* __restrict__ faces,
    float4* __restrict__ rec, uint2* __restrict__ saux,
    unsigned short* __restrict__ stri,
    int F2, int F, int V, int sstride, int sortedFlag)
{
#pragma clang fp contract(off)
    __shared__ unsigned int sk[SORTN];
    int b = blockIdx.x, tid = threadIdx.x;
    const float* ub = uvz + (size_t)b * V * 3;
    const int* fb = faces + (size_t)b * F * 3;
    float4* rb = rec + (size_t)b * F2 * 4;
    uint2* sax = saux + (size_t)b * sstride;
    unsigned short* st = stri + (size_t)b * sstride;

    for (int j = tid; j < F2; j += 1024) {
        int i0, i1, i2;
        if (j < F) { i0 = fb[j*3+0]; i1 = fb[j*3+1]; i2 = fb[j*3+2]; }
        else { int jj = j - F; i0 = fb[jj*3+2]; i1 = fb[jj*3+1]; i2 = fb[jj*3+0]; }
        float ax = ub[i0*3+0], ay = ub[i0*3+1], az = ub[i0*3+2];
        float bx = ub[i1*3+0], by = ub[i1*3+1], bz = ub[i1*3+2];
        float cx = ub[i2*3+0], cy = ub[i2*3+1], cz = ub[i2*3+2];
        float den = (bx-ax)*(cy-ay) - (by-ay)*(cx-ax);
        bool ok = fabsf(den) > 1e-8f;
        float dens = ok ? den : 1.0f;
        bool alive = ok && (az > 1e-8f) && (bz > 1e-8f) && (cz > 1e-8f);
        float za = (az > 1e-8f) ? az : 1.0f;
        float zb = (bz > 1e-8f) ? bz : 1.0f;
        float zc = (cz > 1e-8f) ? cz : 1.0f;
        float mnx = fminf(ax, fminf(bx, cx));
        float mxx = fmaxf(ax, fmaxf(bx, cx));
        float mny = fminf(ay, fminf(by, cy));
        float mxy = fmaxf(ay, fmaxf(by, cy));
        // conservative margin (same logic that passed R1-R4)
        float m = 1e-3f + 1e-6f*((fabsf(mnx)+fabsf(mxx))+(fabsf(mny)+fabsf(mxy)));
        mnx -= m; mxx += m; mny -= m; mxy += m;
        if (!(mxx >= -1.0f) || !(mnx <= 1.0f) || !(mxy >= -1.0f) || !(mny <= 1.0f)) alive = false;
        int ic0 = 1, ic1 = 0, ir0 = 1, ir1 = 0;
        float minz = 3e38f;
        if (alive) {
            float lx = fmaxf(mnx, -1.5f), hx = fminf(mxx, 1.5f);
            float ly = fmaxf(mny, -1.5f), hy = fminf(mxy, 1.5f);
            ic0 = (int)floorf((lx + 1.0f) * 128.0f - 0.5f);
            ic1 = (int)ceilf ((hx + 1.0f) * 128.0f - 0.5f);
            ir0 = (int)floorf((ly + 1.0f) * 128.0f - 0.5f);
            ir1 = (int)ceilf ((hy + 1.0f) * 128.0f - 0.5f);
            ic0 = ic0 < 0 ? 0 : ic0;  ir0 = ir0 < 0 ? 0 : ir0;
            ic1 = ic1 > 255 ? 255 : ic1;  ir1 = ir1 > 255 ? 255 : ir1;
            if (ic0 > ic1 || ir0 > ir1) { ic0 = 1; ic1 = 0; ir0 = 1; ir1 = 0; minz = 3e38f; }
            else minz = fminf(za, fminf(zb, zc)) * (1.0f - 4e-4f);  // conservative early-z key
        }
        float minzv = fminf(za, fminf(zb, zc));
        float maxzv = fmaxf(za, fmaxf(zb, zc));
        float rd = __builtin_amdgcn_rcpf(dens);
        float ra, rbz, rc;
        // approx filter only safe when z's are benign; else force exact path via INF
        if (minzv > 1e-2f && maxzv < 100.0f * minzv) {
            ra  = __builtin_amdgcn_rcpf(za);
            rbz = __builtin_amdgcn_rcpf(zb);
            rc  = __builtin_amdgcn_rcpf(zc);
        } else {
            ra = rbz = rc = __builtin_huge_valf();
        }
        int pack = ic0 | (ic1 << 8) | (ir0 << 16) | (ir1 << 24);
        size_t base = (size_t)j * 4;
        rb[base+0] = make_float4(cx, cy, by - cy, cx - bx);
        rb[base+1] = make_float4(cy - ay, ax - cx, rd, ra);
        rb[base+2] = make_float4(dens, za, zb, zc);
        rb[base+3] = make_float4(__int_as_float(pack), minz, rbz, rc);
        unsigned int kb = __float_as_uint(minz) & 0xFFFFF000u;  // trunc = round-down: conservative
        if (sortedFlag) sk[j] = kb | (unsigned int)j;
        else { sax[j] = make_uint2((unsigned int)pack, kb); st[j] = (unsigned short)j; }
    }
    if (!sortedFlag) return;
    for (int i = tid; i < SORTN; i += 1024)
        if (i >= F2) sk[i] = PADKEY | ((unsigned int)i & 0xFFFu);
    __syncthreads();
    for (int k2 = 2; k2 <= SORTN; k2 <<= 1) {
        for (int j = k2 >> 1; j > 0; j >>= 1) {
            for (int i = tid; i < SORTN; i += 1024) {
                int l = i ^ j;
                if (l > i) {
                    bool asc = (i & k2) == 0;
                    unsigned int a = sk[i], c = sk[l];
                    if ((a > c) == asc) { sk[i] = c; sk[l] = a; }
                }
            }
            __syncthreads();
        }
    }
    for (int i = tid; i < SORTN; i += 1024) {
        unsigned int ky = sk[i];
        unsigned int tri = ky & 0xFFFu;
        unsigned int pk = EMPTYPACK;
        if (ky < PADKEY) pk = __float_as_uint(rb[(size_t)tri*4+3].x);
        else tri = 0;
        sax[i] = make_uint2(pk, ky & 0xFFFFF000u);
        st[i] = (unsigned short)tri;
    }
}

// -------- Kernel 3: tile raster, fused bin-scan, sorted early-z + break ----------
__global__ __launch_bounds__(256) void raster_kernel(
    const float4* __restrict__ rec, const uint2* __restrict__ saux,
    const unsigned short* __restrict__ stri, unsigned int* __restrict__ zbits,
    int F2, int nElems, int sstride, int sortedFlag)
{
#pragma clang fp contract(off)
    __shared__ float4 sh[64*4];
    __shared__ float s_mz[64];
    __shared__ unsigned short s_list[256];
    __shared__ int s_wk[4], s_kk[4], s_wo[4];
    __shared__ int s_tot, s_kc;
    __shared__ float s_tzmax, s_wzx[4];
    int zz = blockIdx.z;
    int b = zz / SPLIT, sp = zz - b*SPLIT;
    int tc = blockIdx.x, tr = blockIdx.y;
    int tid = threadIdx.x, lane = tid & 63, wv = tid >> 6;
    int tx = tid & 15, ty = tid >> 4;
    int col = tc*16 + tx, row = tr*16 + ty;
    float X = gval(col), Y = gval(row);
    int pc0 = tc*16, pc1 = pc0+15, pr0 = tr*16, pr1 = pr0+15;
    const float4* rb = rec + (size_t)b * F2 * 4;
    const uint2* sax = saux + (size_t)b * sstride;
    const unsigned short* st = stri + (size_t)b * sstride;
    float zmin = FARV;
    if (tid == 0) s_tzmax = FARV;
    __syncthreads();
    int nch = (nElems + 256*SPLIT - 1) / (256*SPLIT);
    for (int c = 0; c < nch; ++c) {
        // rank: interleaved at fine granularity so all splits converge on the front
        int s = (c*256 + tid)*SPLIT + sp;
        bool kp = false, sv = false; unsigned int tri = 0;
        if (s < nElems) {
            uint2 a = sax[s];
            float kf = __uint_as_float(a.y);
            kp = !(kf > s_tzmax);                  // conservative early-z (key <= minz)
            if (kp) {
                int pk = (int)a.x;
                int ic0 = pk & 255, ic1 = (pk >> 8) & 255;
                int ir0 = (pk >> 16) & 255, ir1 = (pk >> 24) & 255;
                sv = (ic0 <= ic1) && (ic0 <= pc1) && (ic1 >= pc0) && (ir0 <= pr1) && (ir1 >= pr0);
                if (sv) tri = st[s];
            }
        }
        unsigned long long bs = __ballot(sv ? 1 : 0);
        unsigned long long bk = __ballot(kp ? 1 : 0);
        int pfx = __popcll(bs & ((1ull << lane) - 1ull));
        if (lane == 0) { s_wk[wv] = __popcll(bs); s_kk[wv] = __popcll(bk); }
        __syncthreads();
        if (tid == 0) {
            int acc = 0;
            for (int q = 0; q < 4; ++q) { s_wo[q] = acc; acc += s_wk[q]; }
            s_tot = acc;
            s_kc = s_kk[0] + s_kk[1] + s_kk[2] + s_kk[3];
        }
        __syncthreads();
        if (sv) s_list[s_wo[wv] + pfx] = (unsigned short)tri;
        int kcnt = s_kc, n = s_tot;
        if (kcnt == 0) {
            // ascending keys: all remaining in my subsequence are also > tzmax
            if (sortedFlag) break; else continue;
        }
        for (int g = 0; g < n; g += 64) {
            __syncthreads();                       // s_list ready / sh reusable
            int cnt = (n - g) < 64 ? (n - g) : 64;
            if (tid < cnt*4) {
                unsigned int t4 = s_list[g + (tid >> 2)];
                float4 f = rb[(size_t)t4*4 + (tid & 3)];
                sh[tid] = f;
                if ((tid & 3) == 3) s_mz[tid >> 2] = f.y;
            }
            __syncthreads();
            for (int i = 0; i < cnt; ++i) {
                float mz = s_mz[i];                // 4B broadcast: cheap skip
                if (mz > zmin) continue;
                float4 q3 = sh[i*4+3];
                int pk = __float_as_int(q3.x);
                int ic0 = pk & 255, ic1 = (pk >> 8) & 255;
                int ir0 = (pk >> 16) & 255, ir1 = (pk >> 24) & 255;
                if (col < ic0 || col > ic1 || row < ir0 || row > ir1) continue;
                float4 q0 = sh[i*4+0];
                float4 q1 = sh[i*4+1];
                float xc = X - q0.x;
                float yc = Y - q0.y;
                float e0 = (q0.z*xc) + (q0.w*yc);  // w0 numerator, bit-exact vs ref
                float e1 = (q1.x*xc) + (q1.y*yc);  // w1 numerator
                float rd = q1.z;
                float sgn = copysignf(1.0f, rd);   // sign(rd) == sign(dens)
                float s0 = e0*sgn, s1 = e1*sgn;
                float w0a = e0*rd, w1a = e1*rd;    // approx w (filter only)
                float w2a = (1.0f - w0a) - w1a;
                float epsu = 1e-4f*((1.0f + fabsf(w0a)) + fabsf(w1a));
                // conservative candidate filter; exact tests inside decide
                if (s0 > -1e-30f && s1 > -1e-30f && w2a > -epsu) {
                    float inva = ((w0a*q1.w) + (w1a*q3.z)) + (w2a*q3.w);
                    float zpa = __builtin_amdgcn_rcpf(inva);
                    bool clearly = (s0 > 0.0f) && (s1 > 0.0f) && (w2a > epsu) && (inva > 1e-6f);
                    // clearly-valid + approx-zp above zmin (w/ 1e-3 margin) provably
                    // cannot change the exact min -> skip the 6 IEEE divides
                    if (!clearly || zpa < zmin*1.001f) {
                        float4 q2 = sh[i*4+2];
                        float dens = q2.x;
                        float w0 = e0 / dens;      // IEEE div == ref
                        float w1 = e1 / dens;
                        float w2 = (1.0f - w0) - w1;
                        float inv = ((w0 / q2.y) + (w1 / q2.z)) + (w2 / q2.w);
                        if ((w0 >= 0.0f) && (w1 >= 0.0f) && (w2 >= 0.0f) && (inv > 1e-8f)) {
                            float zp = 1.0f / inv; // exact div == ref zp
                            zmin = fminf(zmin, zp);
                        }
                    }
                }
            }
        }
        if (n > 0) {
            // refresh conservative tile-wide zmax (only shrinks -> stays conservative)
            float zx = zmin;
            for (int o = 32; o; o >>= 1) zx = fmaxf(zx, __shfl_xor(zx, o));
            if (lane == 0) s_wzx[wv] = zx;
        }
        __syncthreads();
        if (n > 0 && tid == 0)
            s_tzmax = fmaxf(fmaxf(s_wzx[0], s_wzx[1]), fmaxf(s_wzx[2], s_wzx[3]));
        __syncthreads();
    }
    if (zmin < FARV) {
        size_t pix = ((size_t)b*RASTN + row)*RASTN + col;
        atomicMin(zbits + pix, __float_as_uint(zmin));   // positive floats: bit-monotone
    }
}

// -------- Kernel 4: per-batch max(no_back)/min reduction -------------------------
__global__ __launch_bounds__(256) void minmax_kernel(
    const float* __restrict__ zbuf, unsigned int* __restrict__ mm, int seg)
{
    __shared__ float smx[4], smn[4];
    int b = blockIdx.y;
    const float* p = zbuf + (size_t)b * (RASTN*RASTN) + (size_t)blockIdx.x * seg;
    int lane = threadIdx.x & 63, wv = threadIdx.x >> 6;
    float vmx = 0.0f, vmn = FARV;
    for (int i = threadIdx.x; i < seg; i += 256) {
        float z = p[i];
        float nb = (z == FARV) ? 0.0f : z;   // (1-img_inf)*img
        vmx = fmaxf(vmx, nb);
        vmn = fminf(vmn, z);
    }
    for (int o = 32; o; o >>= 1) {
        vmx = fmaxf(vmx, __shfl_xor(vmx, o));
        vmn = fminf(vmn, __shfl_xor(vmn, o));
    }
    if (lane == 0) { smx[wv] = vmx; smn[wv] = vmn; }
    __syncthreads();
    if (threadIdx.x == 0) {
        float bmx = fmaxf(fmaxf(smx[0], smx[1]), fmaxf(smx[2], smx[3]));
        float bmn = fminf(fminf(smn[0], smn[1]), fminf(smn[2], smn[3]));
        atomicMax(mm + 2*b,     __float_as_uint(bmx));
        atomicMin(mm + 2*b + 1, __float_as_uint(bmn));
    }
}

// -------- Kernel 5: normalize depth in place + write mask ------------------------
__global__ __launch_bounds__(256) void final_kernel(
    float* __restrict__ zdep, float* __restrict__ mask,
    const unsigned int* __restrict__ mm, int npix, int total)
{
#pragma clang fp contract(off)
    int idx = blockIdx.x*256 + threadIdx.x;
    if (idx >= total) return;
    int b = idx / npix;
    float mx = __uint_as_float(mm[2*b]);
    float mn = __uint_as_float(mm[2*b + 1]);
    float z = zdep[idx];
    // cover == any valid hit == (z < FAR): valid hits have zp <= ~1.25 << 10
    mask[idx] = (z < FARV) ? 1.0f : 0.0f;
    float nd = (mx - z) / ((mx - mn) + 1e-4f);
    float cv = nd;
    cv = (cv < 0.0f) ? 0.0f : cv;
    cv = (cv > 1.0f) ? 1.0f : cv;
    zdep[idx] = cv;
}

extern "C" void kernel_launch(void* const* d_in, const int* in_sizes, int n_in,
                              void* d_out, int out_size, void* d_ws, size_t ws_size,
                              hipStream_t stream)
{
    const float* verts = (const float*)d_in[0];
    const int*   faces = (const int*)d_in[1];
    const float* Km    = (const float*)d_in[2];
    const float* Rm    = (const float*)d_in[3];
    const float* tm    = (const float*)d_in[4];
    const float* dm    = (const float*)d_in[5];
    float* out = (float*)d_out;

    int B  = in_sizes[2] / 9;          // intr is B*3*3
    int V  = in_sizes[0] / (3 * B);
    int F  = in_sizes[1] / (3 * B);
    int F2 = 2 * F;
    int npix = RASTN * RASTN;
    int sortedFlag = (F2 <= SORTN) ? 1 : 0;
    int sstride = (F2 > SORTN) ? F2 : SORTN;

    char* ws = (char*)d_ws;
    size_t off = 0;
    float* uvz = (float*)(ws + off);
    off = (off + (size_t)B * V * 3 * sizeof(float) + 255) & ~(size_t)255;
    float4* rec = (float4*)(ws + off);
    off = (off + (size_t)B * F2 * 4 * sizeof(float4) + 255) & ~(size_t)255;
    uint2* saux = (uint2*)(ws + off);
    off = (off + (size_t)B * sstride * sizeof(uint2) + 255) & ~(size_t)255;
    unsigned short* stri = (unsigned short*)(ws + off);
    off = (off + (size_t)B * sstride * sizeof(unsigned short) + 255) & ~(size_t)255;
    unsigned int* mm = (unsigned int*)(ws + off);

    float* zdep = out;                       // depth region doubles as zbuf
    float* mask = out + (size_t)B * npix;

    int totV = B * V;
    int n4 = (B * npix) / 4;
    int N1 = totV > n4 ? totV : n4;
    if (2*B > N1) N1 = 2*B;
    proj_init_kernel<<<(N1 + 255) / 256, 256, 0, stream>>>(
        verts, Km, Rm, tm, dm, uvz, mm, (uint4*)zdep, totV, V, B, n4);
    prep_sort_kernel<<<B, 1024, 0, stream>>>(
        uvz, faces, rec, saux, stri, F2, F, V, sstride, sortedFlag);
    int nElems = sortedFlag ? SORTN : F2;
    dim3 rgrid(16, 16, B * SPLIT);
    raster_kernel<<<rgrid, 256, 0, stream>>>(
        rec, saux, stri, (unsigned int*)zdep, F2, nElems, sstride, sortedFlag);
    int seg = npix / 16;
    dim3 mgrid(16, B);
    minmax_kernel<<<mgrid, 256, 0, stream>>>(zdep, mm, seg);
    final_kernel<<<(B * npix + 255) / 256, 256, 0, stream>>>(zdep, mask, mm, npix, B * npix);
}